// Round 1
// baseline (2609.948 us; speedup 1.0000x reference)
//
#include <hip/hip_runtime.h>
#include <math.h>

// fp32 attention layer via split-bf16 (hi/lo) 3-term MFMA emulation.
// Pipeline: split(x,Wqkv) -> GEMM1(qkv, writes hi/lo planes) -> transpose V
//           -> split(Wo) -> flash attention -> GEMM2(o_proj + bias, fp32 out)

typedef unsigned int u32;
typedef unsigned short u16;
typedef __attribute__((ext_vector_type(8))) short bf16x8;
typedef __attribute__((ext_vector_type(4))) float f32x4;

#define MFMA(a, b, c) __builtin_amdgcn_mfma_f32_16x16x32_bf16((a), (b), (c), 0, 0, 0)

#define GLDS16(g, l) __builtin_amdgcn_global_load_lds( \
    (const __attribute__((address_space(1))) u32*)(g), \
    (__attribute__((address_space(3))) u32*)(l), 16, 0, 0)

__device__ __forceinline__ u16 f2bf(float f) {
  u32 u = __builtin_bit_cast(u32, f);
  return (u16)((u + 0x7fffu + ((u >> 16) & 1u)) >> 16);  // RNE
}
__device__ __forceinline__ float bf2f(u16 h) {
  u32 u = ((u32)h) << 16;
  return __builtin_bit_cast(float, u);
}
__device__ __forceinline__ void split2(float f, u16& h, u16& l) {
  h = f2bf(f);
  l = f2bf(f - bf2f(h));
}
__device__ __forceinline__ bf16x8 ld16(const u16* p) {
  return *reinterpret_cast<const bf16x8*>(p);
}

// ---------------------------------------------------------------- split ----
__global__ void split_kernel(const float* __restrict__ src, u16* __restrict__ hi,
                             u16* __restrict__ lo, long n) {
  long i = ((long)blockIdx.x * 256 + threadIdx.x) * 4;
  if (i >= n) return;
  const float4 v = *reinterpret_cast<const float4*>(src + i);
  ushort4 h, l;
  split2(v.x, h.x, l.x);
  split2(v.y, h.y, l.y);
  split2(v.z, h.z, l.z);
  split2(v.w, h.w, l.w);
  *reinterpret_cast<ushort4*>(hi + i) = h;
  *reinterpret_cast<ushort4*>(lo + i) = l;
}

// ----------------------------------------------------------------- gemm ----
// C[M,N] = A[M,K] * B[N,K]^T with A,B given as hi/lo bf16 planes.
// MODE 0: write C as hi/lo bf16 planes.  MODE 1: fp32 C + bias[col].
// 128x128 tile, BK=32, 256 threads = 4 waves in 2x2, each wave 64x64 (4x4
// frags of 16x16x32). global_load_lds width-16 staging (m97 structure).
template <int MODE>
__global__ __launch_bounds__(256, 2) void gemm_nt_split(
    const u16* __restrict__ Ah, const u16* __restrict__ Al,
    const u16* __restrict__ Bh, const u16* __restrict__ Bl,
    int M, int N, int K,
    u16* __restrict__ Ch, u16* __restrict__ Cl,
    float* __restrict__ Cf, const float* __restrict__ bias) {
  __shared__ u16 sAh[128 * 32], sAl[128 * 32], sBh[128 * 32], sBl[128 * 32];
  const int tid = threadIdx.x;
  const int lane = tid & 63;
  const int wv = tid >> 6;
  const int wr = wv >> 1, wc = wv & 1;
  const int lr = lane & 15, lg = lane >> 4;

  const int mt = M >> 7;
  const int nwg = gridDim.x;
  const int bid = blockIdx.x;
  // XCD-aware swizzle (nwg divisible by 8 for all our grids)
  const int wg = (bid & 7) * (nwg >> 3) + (bid >> 3);
  const int bm = wg % mt;  // consecutive wg share the B panel (L2 locality)
  const int bn = wg / mt;

  const int srow = lane >> 2;       // staging: row within 16-row chunk
  const int scol = (lane & 3) * 8;  // staging: k offset (8 elems = 16B)

  f32x4 acc[4][4];
#pragma unroll
  for (int m = 0; m < 4; ++m)
#pragma unroll
    for (int n = 0; n < 4; ++n)
#pragma unroll
      for (int j = 0; j < 4; ++j) acc[m][n][j] = 0.f;

  for (int k0 = 0; k0 < K; k0 += 32) {
#pragma unroll
    for (int i = 0; i < 2; ++i) {
      const int chunk = wv * 2 + i;  // 8 chunks of 16 rows each
      const long gA = ((long)(bm * 128 + chunk * 16 + srow)) * K + k0 + scol;
      const long gB = ((long)(bn * 128 + chunk * 16 + srow)) * K + k0 + scol;
      GLDS16(Ah + gA, &sAh[chunk * 512]);
      GLDS16(Al + gA, &sAl[chunk * 512]);
      GLDS16(Bh + gB, &sBh[chunk * 512]);
      GLDS16(Bl + gB, &sBl[chunk * 512]);
    }
    __syncthreads();  // compiler emits vmcnt(0) drain before barrier
    bf16x8 ah[4], al[4];
#pragma unroll
    for (int m = 0; m < 4; ++m) {
      const int arow = wr * 64 + m * 16 + lr;
      ah[m] = ld16(&sAh[arow * 32 + lg * 8]);
      al[m] = ld16(&sAl[arow * 32 + lg * 8]);
    }
#pragma unroll
    for (int n = 0; n < 4; ++n) {
      const int brow = wc * 64 + n * 16 + lr;
      const bf16x8 bh = ld16(&sBh[brow * 32 + lg * 8]);
      const bf16x8 bl = ld16(&sBl[brow * 32 + lg * 8]);
#pragma unroll
      for (int m = 0; m < 4; ++m) {
        acc[m][n] = MFMA(ah[m], bh, acc[m][n]);
        acc[m][n] = MFMA(ah[m], bl, acc[m][n]);
        acc[m][n] = MFMA(al[m], bh, acc[m][n]);
      }
    }
    __syncthreads();
  }

  // epilogue: C/D layout col=lane&15, row=(lane>>4)*4+j (m89-verified)
#pragma unroll
  for (int m = 0; m < 4; ++m)
#pragma unroll
    for (int j = 0; j < 4; ++j) {
      const long row = (long)bm * 128 + wr * 64 + m * 16 + lg * 4 + j;
#pragma unroll
      for (int n = 0; n < 4; ++n) {
        const long col = (long)bn * 128 + wc * 64 + n * 16 + lr;
        const long idx = row * N + col;
        const float v = acc[m][n][j];
        if (MODE == 0) {
          u16 h, l;
          split2(v, h, l);
          Ch[idx] = h;
          Cl[idx] = l;
        } else {
          Cf[idx] = v + bias[col];
        }
      }
    }
}

// ----------------------------------------------------------- V transpose ---
// qkv V-third [b*2048+s][6144 + h*96 + d] -> VT[(b*32+h)*96 + d][s]
__global__ void transpose_v(const u16* __restrict__ QKVh, const u16* __restrict__ QKVl,
                            u16* __restrict__ VTh, u16* __restrict__ VTl) {
  const int bid = blockIdx.x;  // [b*32+h (64)][schunk (16)]
  const int schunk = bid & 15;
  const int hl = bid >> 4;
  const int s0 = schunk * 128;
  for (int idx = threadIdx.x; idx < 96 * 128; idx += 256) {
    const int s = idx / 96;
    const int d = idx - s * 96;
    const long src = ((long)((hl >> 5) * 2048 + s0 + s)) * 9216 + 6144 + (hl & 31) * 96 + d;
    const long dst = ((long)hl * 96 + d) * 2048 + s0 + s;
    VTh[dst] = QKVh[src];
    VTl[dst] = QKVl[src];
  }
}

// ------------------------------------------------------------- attention ---
// One wave = 16 independent q rows. Block = 4 waves. Flash/online softmax.
// QK^T: A=Q frag (global 16B loads), B=K^T frag (global 16B loads, L2-hot).
// P goes C-layout -> A-layout through wave-private LDS. PV uses V^T planes.
__global__ __launch_bounds__(256, 2) void attn_kernel(
    const u16* __restrict__ QKVh, const u16* __restrict__ QKVl,
    const u16* __restrict__ VTh, const u16* __restrict__ VTl,
    u16* __restrict__ AOh, u16* __restrict__ AOl) {
  __shared__ u16 pb[4][2][512];  // [wave][hi/lo][16x32 P tile]
  const int lane = threadIdx.x & 63;
  const int wv = threadIdx.x >> 6;
  const int lr = lane & 15, lg = lane >> 4;

  const int nwg = gridDim.x;
  const int bid = blockIdx.x;
  const int wg = (bid & 7) * (nwg >> 3) + (bid >> 3);  // XCD swizzle: head's
  const int hl = wg >> 5;                              // q-tiles stay on one XCD
  const int qblk = wg & 31;
  const int b = hl >> 5;
  const int q0 = qblk * 64 + wv * 16;

  bf16x8 qh[3], ql[3];
  {
    const long qofs = ((long)(b * 2048 + q0 + lr)) * 9216 + (hl & 31) * 96 + lg * 8;
#pragma unroll
    for (int c = 0; c < 3; ++c) {
      qh[c] = ld16(QKVh + qofs + c * 32);
      ql[c] = ld16(QKVl + qofs + c * 32);
    }
  }

  f32x4 o_acc[6];
#pragma unroll
  for (int n = 0; n < 6; ++n)
#pragma unroll
    for (int j = 0; j < 4; ++j) o_acc[n][j] = 0.f;

  float m_run[4] = {-INFINITY, -INFINITY, -INFINITY, -INFINITY};
  float l_run[4] = {0.f, 0.f, 0.f, 0.f};

  const long kbase = ((long)(b * 2048 + lr)) * 9216 + 3072 + (hl & 31) * 96 + lg * 8;
  const long vbase = ((long)hl * 96 + lr) * 2048 + lg * 8;
  u16* pbh = pb[wv][0];
  u16* pbl = pb[wv][1];
  const float scale = 0.10206207261596577f;  // 96^-0.5

  for (int kv0 = 0; kv0 < 2048; kv0 += 32) {
    f32x4 s0, s1;
#pragma unroll
    for (int j = 0; j < 4; ++j) { s0[j] = 0.f; s1[j] = 0.f; }
#pragma unroll
    for (int c = 0; c < 3; ++c) {
      const long o0 = kbase + (long)kv0 * 9216 + c * 32;
      const long o1 = kbase + (long)(kv0 + 16) * 9216 + c * 32;
      const bf16x8 kh0 = ld16(QKVh + o0), kl0 = ld16(QKVl + o0);
      const bf16x8 kh1 = ld16(QKVh + o1), kl1 = ld16(QKVl + o1);
      s0 = MFMA(qh[c], kh0, s0);
      s0 = MFMA(qh[c], kl0, s0);
      s0 = MFMA(ql[c], kh0, s0);
      s1 = MFMA(qh[c], kh1, s1);
      s1 = MFMA(qh[c], kl1, s1);
      s1 = MFMA(ql[c], kh1, s1);
    }
    // online softmax; rows r = lg*4+j, cols = lr (tile0) / lr+16 (tile1).
    // xor masks 1,2,4,8 only touch low 4 lane bits -> stay in the 16-group.
    float corr[4];
#pragma unroll
    for (int j = 0; j < 4; ++j) {
      const float v0 = s0[j] * scale, v1 = s1[j] * scale;
      float mt = fmaxf(v0, v1);
#pragma unroll
      for (int mk = 1; mk < 16; mk <<= 1) mt = fmaxf(mt, __shfl_xor(mt, mk));
      const float mnew = fmaxf(m_run[j], mt);
      const float c0 = __expf(m_run[j] - mnew);  // first iter: exp(-inf)=0
      const float p0 = __expf(v0 - mnew);
      const float p1 = __expf(v1 - mnew);
      float rs = p0 + p1;
#pragma unroll
      for (int mk = 1; mk < 16; mk <<= 1) rs += __shfl_xor(rs, mk);
      l_run[j] = l_run[j] * c0 + rs;
      m_run[j] = mnew;
      corr[j] = c0;
      const int r = lg * 4 + j;
      u16 h0, l0, h1, l1;
      split2(p0, h0, l0);
      split2(p1, h1, l1);
      pbh[r * 32 + lr] = h0;
      pbl[r * 32 + lr] = l0;
      pbh[r * 32 + lr + 16] = h1;
      pbl[r * 32 + lr + 16] = l1;
    }
#pragma unroll
    for (int n = 0; n < 6; ++n)
#pragma unroll
      for (int j = 0; j < 4; ++j) o_acc[n][j] *= corr[j];
    __syncthreads();  // P write -> P read ordering (uniform, cheap)
    const bf16x8 pah = ld16(&pbh[lr * 32 + lg * 8]);
    const bf16x8 pal = ld16(&pbl[lr * 32 + lg * 8]);
#pragma unroll
    for (int n = 0; n < 6; ++n) {
      const long vo = vbase + (long)n * 16 * 2048 + kv0;
      const bf16x8 vh = ld16(VTh + vo);
      const bf16x8 vl = ld16(VTl + vo);
      o_acc[n] = MFMA(pah, vh, o_acc[n]);
      o_acc[n] = MFMA(pah, vl, o_acc[n]);
      o_acc[n] = MFMA(pal, vh, o_acc[n]);
    }
  }

  float inv[4];
#pragma unroll
  for (int j = 0; j < 4; ++j) inv[j] = 1.f / l_run[j];
#pragma unroll
  for (int n = 0; n < 6; ++n)
#pragma unroll
    for (int j = 0; j < 4; ++j) {
      const long row = (long)(b * 2048 + q0 + lg * 4 + j);
      const long col = (long)(hl & 31) * 96 + n * 16 + lr;
      u16 h, l;
      split2(o_acc[n][j] * inv[j], h, l);
      AOh[row * 3072 + col] = h;
      AOl[row * 3072 + col] = l;
    }
}

// ---------------------------------------------------------------- launch ---
extern "C" void kernel_launch(void* const* d_in, const int* in_sizes, int n_in,
                              void* d_out, int out_size, void* d_ws, size_t ws_size,
                              hipStream_t stream) {
  const float* x = (const float*)d_in[0];     // [4096][3072]
  const float* wqkv = (const float*)d_in[1];  // [9216][3072]
  const float* wo = (const float*)d_in[2];    // [3072][3072]
  const float* bo = (const float*)d_in[3];    // [3072]
  float* out = (float*)d_out;                 // [4096][3072]
  char* ws = (char*)d_ws;

  const size_t E_X = (size_t)4096 * 3072;
  const size_t E_WQ = (size_t)9216 * 3072;
  const size_t E_QKV = (size_t)4096 * 9216;
  const size_t E_WO = (size_t)3072 * 3072;

  // layout: [X planes | WQKV planes | QKV planes | VT planes]
  // after GEMM1, WQKV region is dead -> reused for AO planes + WO planes.
  u16* XH = (u16*)ws;
  u16* XL = XH + E_X;
  char* W0 = ws + 4 * E_X;  // 2 planes * 2B
  u16* WQH = (u16*)W0;
  u16* WQL = WQH + E_WQ;
  char* Q0 = W0 + 4 * E_WQ;
  u16* QKVH = (u16*)Q0;
  u16* QKVL = QKVH + E_QKV;
  char* V0 = Q0 + 4 * E_QKV;
  u16* VTH = (u16*)V0;
  u16* VTL = VTH + E_X;
  // overlapped reuse of the WQKV region:
  u16* AOH = (u16*)W0;               // 50.3 MB
  u16* AOL = AOH + E_X;
  u16* WOH = (u16*)(W0 + 4 * E_X);   // +37.7 MB = 88.1 MB < 113.2 MB region
  u16* WOL = WOH + E_WO;

  const size_t need = 4 * (E_X + E_WQ + E_QKV + E_X);  // 364.9 MB
  if (ws_size < need) return;  // diagnostic: validation fails cleanly

  split_kernel<<<12288, 256, 0, stream>>>(x, XH, XL, (long)E_X);
  split_kernel<<<27648, 256, 0, stream>>>(wqkv, WQH, WQL, (long)E_WQ);
  gemm_nt_split<0><<<2304, 256, 0, stream>>>(XH, XL, WQH, WQL, 4096, 9216, 3072,
                                             QKVH, QKVL, nullptr, nullptr);
  transpose_v<<<1024, 256, 0, stream>>>(QKVH, QKVL, VTH, VTL);
  split_kernel<<<9216, 256, 0, stream>>>(wo, WOH, WOL, (long)E_WO);
  attn_kernel<<<2048, 256, 0, stream>>>(QKVH, QKVL, VTH, VTL, AOH, AOL);
  gemm_nt_split<1><<<768, 256, 0, stream>>>(AOH, AOL, WOH, WOL, 4096, 3072, 3072,
                                            nullptr, nullptr, out, bo);
}

// Round 2
// 1533.735 us; speedup vs baseline: 1.7017x; 1.7017x over previous
//
#include <hip/hip_runtime.h>
#include <math.h>

// fp32 attention layer via split-bf16 (hi/lo) 3-term MFMA emulation.
// Pipeline: split(x,Wqkv) -> GEMM1(qkv planes) -> pack K/V into wave-frag
// records -> split(Wo) -> flash attention (LDS-staged, max-free softmax)
// -> GEMM2(o_proj + bias, fp32 out)

typedef unsigned int u32;
typedef unsigned short u16;
typedef __attribute__((ext_vector_type(8))) short bf16x8;
typedef __attribute__((ext_vector_type(4))) float f32x4;

#define MFMA(a, b, c) __builtin_amdgcn_mfma_f32_16x16x32_bf16((a), (b), (c), 0, 0, 0)

#define GLDS16(g, l) __builtin_amdgcn_global_load_lds( \
    (const __attribute__((address_space(1))) u32*)(g), \
    (__attribute__((address_space(3))) u32*)(l), 16, 0, 0)

__device__ __forceinline__ u16 f2bf(float f) {
  u32 u = __builtin_bit_cast(u32, f);
  return (u16)((u + 0x7fffu + ((u >> 16) & 1u)) >> 16);  // RNE
}
__device__ __forceinline__ float bf2f(u16 h) {
  u32 u = ((u32)h) << 16;
  return __builtin_bit_cast(float, u);
}
__device__ __forceinline__ void split2(float f, u16& h, u16& l) {
  h = f2bf(f);
  l = f2bf(f - bf2f(h));
}
__device__ __forceinline__ bf16x8 ld16(const u16* p) {
  return *reinterpret_cast<const bf16x8*>(p);
}

// ---------------------------------------------------------------- split ----
__global__ void split_kernel(const float* __restrict__ src, u16* __restrict__ hi,
                             u16* __restrict__ lo, long n) {
  long i = ((long)blockIdx.x * 256 + threadIdx.x) * 4;
  if (i >= n) return;
  const float4 v = *reinterpret_cast<const float4*>(src + i);
  ushort4 h, l;
  split2(v.x, h.x, l.x);
  split2(v.y, h.y, l.y);
  split2(v.z, h.z, l.z);
  split2(v.w, h.w, l.w);
  *reinterpret_cast<ushort4*>(hi + i) = h;
  *reinterpret_cast<ushort4*>(lo + i) = l;
}

// ----------------------------------------------------------------- gemm ----
// C[M,N] = A[M,K] * B[N,K]^T with A,B given as hi/lo bf16 planes.
// MODE 0: write C as hi/lo bf16 planes.  MODE 1: fp32 C + bias[col].
template <int MODE>
__global__ __launch_bounds__(256, 2) void gemm_nt_split(
    const u16* __restrict__ Ah, const u16* __restrict__ Al,
    const u16* __restrict__ Bh, const u16* __restrict__ Bl,
    int M, int N, int K,
    u16* __restrict__ Ch, u16* __restrict__ Cl,
    float* __restrict__ Cf, const float* __restrict__ bias) {
  __shared__ u16 sAh[128 * 32], sAl[128 * 32], sBh[128 * 32], sBl[128 * 32];
  const int tid = threadIdx.x;
  const int lane = tid & 63;
  const int wv = tid >> 6;
  const int wr = wv >> 1, wc = wv & 1;
  const int lr = lane & 15, lg = lane >> 4;

  const int mt = M >> 7;
  const int nwg = gridDim.x;
  const int bid = blockIdx.x;
  const int wg = (bid & 7) * (nwg >> 3) + (bid >> 3);  // XCD swizzle
  const int bm = wg % mt;
  const int bn = wg / mt;

  const int srow = lane >> 2;
  const int scol = (lane & 3) * 8;

  f32x4 acc[4][4];
#pragma unroll
  for (int m = 0; m < 4; ++m)
#pragma unroll
    for (int n = 0; n < 4; ++n)
#pragma unroll
      for (int j = 0; j < 4; ++j) acc[m][n][j] = 0.f;

  for (int k0 = 0; k0 < K; k0 += 32) {
#pragma unroll
    for (int i = 0; i < 2; ++i) {
      const int chunk = wv * 2 + i;
      const long gA = ((long)(bm * 128 + chunk * 16 + srow)) * K + k0 + scol;
      const long gB = ((long)(bn * 128 + chunk * 16 + srow)) * K + k0 + scol;
      GLDS16(Ah + gA, &sAh[chunk * 512]);
      GLDS16(Al + gA, &sAl[chunk * 512]);
      GLDS16(Bh + gB, &sBh[chunk * 512]);
      GLDS16(Bl + gB, &sBl[chunk * 512]);
    }
    __syncthreads();
    bf16x8 ah[4], al[4];
#pragma unroll
    for (int m = 0; m < 4; ++m) {
      const int arow = wr * 64 + m * 16 + lr;
      ah[m] = ld16(&sAh[arow * 32 + lg * 8]);
      al[m] = ld16(&sAl[arow * 32 + lg * 8]);
    }
#pragma unroll
    for (int n = 0; n < 4; ++n) {
      const int brow = wc * 64 + n * 16 + lr;
      const bf16x8 bh = ld16(&sBh[brow * 32 + lg * 8]);
      const bf16x8 bl = ld16(&sBl[brow * 32 + lg * 8]);
#pragma unroll
      for (int m = 0; m < 4; ++m) {
        acc[m][n] = MFMA(ah[m], bh, acc[m][n]);
        acc[m][n] = MFMA(ah[m], bl, acc[m][n]);
        acc[m][n] = MFMA(al[m], bh, acc[m][n]);
      }
    }
    __syncthreads();
  }

#pragma unroll
  for (int m = 0; m < 4; ++m)
#pragma unroll
    for (int j = 0; j < 4; ++j) {
      const long row = (long)bm * 128 + wr * 64 + m * 16 + lg * 4 + j;
#pragma unroll
      for (int n = 0; n < 4; ++n) {
        const long col = (long)bn * 128 + wc * 64 + n * 16 + lr;
        const long idx = row * N + col;
        const float v = acc[m][n][j];
        if (MODE == 0) {
          u16 h, l;
          split2(v, h, l);
          Ch[idx] = h;
          Cl[idx] = l;
        } else {
          Cf[idx] = v + bias[col];
        }
      }
    }
}

// ---------------------------------------------------------------- pack K ---
// K records: rec3 = (hl*128 + kb)*3 + c; record pair (hi at rec3*2, lo at
// rec3*2+1), each 512 elems: lane l=(lr,lg) holds K[kb*16+lr][c*32+lg*8 ..+8].
__global__ void pack_k(const u16* __restrict__ QKVh, const u16* __restrict__ QKVl,
                       u16* __restrict__ Kp) {
  const int t = blockIdx.x * 256 + threadIdx.x;
  const int lane = t & 63;
  const int rec3 = t >> 6;
  const int c = rec3 % 3;
  const int kb = (rec3 / 3) & 127;
  const int hl = rec3 / 384;
  const int lr = lane & 15, lg = lane >> 4;
  const long src =
      ((long)((hl >> 5) * 2048 + kb * 16 + lr)) * 9216 + 3072 + (hl & 31) * 96 + c * 32 + lg * 8;
  const long dst = ((long)rec3 * 2) * 512 + lane * 8;
  *reinterpret_cast<bf16x8*>(Kp + dst) = ld16(QKVh + src);
  *reinterpret_cast<bf16x8*>(Kp + dst + 512) = ld16(QKVl + src);
}

// ---------------------------------------------------------------- pack V ---
// V records: rec = ((hl*6 + n)*64 + kq)*2 + pl; lane l=(lr,lg) holds
// V^T[n*16+lr][kq*32 + lg*8 ..+8]. Staged through LDS for coalescing.
__global__ __launch_bounds__(256) void pack_v(const u16* __restrict__ QKVh,
                                              const u16* __restrict__ QKVl,
                                              u16* __restrict__ Vp) {
  __shared__ u16 sV[2][32 * 96];
  const int tid = threadIdx.x;
  const int hl = blockIdx.x >> 6;
  const int kq = blockIdx.x & 63;
  const long rowbase = ((long)((hl >> 5) * 2048 + kq * 32)) * 9216 + 6144 + (hl & 31) * 96;
#pragma unroll
  for (int i = 0; i < 3; ++i) {
    const int idx = i * 256 + tid;  // 768 chunks: [pl][row(32)][cu(12)]
    const int pl = idx / 384;
    const int r2 = idx % 384;
    const int row = r2 / 12, cu = r2 % 12;
    const u16* srcp = (pl ? QKVl : QKVh) + rowbase + (long)row * 9216 + cu * 8;
    *reinterpret_cast<bf16x8*>(&sV[pl][row * 96 + cu * 8]) = ld16(srcp);
  }
  __syncthreads();
#pragma unroll
  for (int i = 0; i < 3; ++i) {
    const int idx = i * 256 + tid;  // 12 recs x 64 lanes
    const int lane = idx & 63;
    const int rl = idx >> 6;
    const int n = rl >> 1, pl = rl & 1;
    const int lr = lane & 15, lg = lane >> 4;
    bf16x8 o;
#pragma unroll
    for (int e = 0; e < 8; ++e) o[e] = (short)sV[pl][(lg * 8 + e) * 96 + n * 16 + lr];
    const long dst = ((((long)hl * 6 + n) * 64 + kq) * 2 + pl) * 512 + lane * 8;
    *reinterpret_cast<bf16x8*>(Vp + dst) = o;
  }
}

// ------------------------------------------------------------- attention ---
// Block = 4 waves, one (head, 64-q-row tile); wave owns 16 q rows. Per
// 32-kv-row iteration: 24 packed records (24KB) staged once per block via
// global_load_lds (6 per wave), double-buffered; all waves ds_read the shared
// copy. Max-free softmax: p = exp(s*scale - 12); l-sum reduced once at end.
__global__ __launch_bounds__(256, 2) void attn_kernel(
    const u16* __restrict__ QKVh, const u16* __restrict__ QKVl,
    const u16* __restrict__ Kp, const u16* __restrict__ Vp,
    u16* __restrict__ AOh, u16* __restrict__ AOl) {
  __shared__ u16 kv[2][24 * 512];  // 48 KB double-buffered K/V records
  __shared__ u16 pb[4][2][512];    // 8 KB wave-private P tiles
  const int lane = threadIdx.x & 63;
  const int wv = threadIdx.x >> 6;
  const int lr = lane & 15, lg = lane >> 4;

  const int nwg = gridDim.x;
  const int bid = blockIdx.x;
  const int wg = (bid & 7) * (nwg >> 3) + (bid >> 3);  // XCD swizzle
  const int hl = wg >> 5;
  const int qblk = wg & 31;
  const int b = hl >> 5;
  const int q0 = qblk * 64 + wv * 16;

  bf16x8 qh[3], ql[3];
  {
    const long qofs = ((long)(b * 2048 + q0 + lr)) * 9216 + (hl & 31) * 96 + lg * 8;
#pragma unroll
    for (int c = 0; c < 3; ++c) {
      qh[c] = ld16(QKVh + qofs + c * 32);
      ql[c] = ld16(QKVl + qofs + c * 32);
    }
  }

  f32x4 o_acc[6];
#pragma unroll
  for (int n = 0; n < 6; ++n)
#pragma unroll
    for (int j = 0; j < 4; ++j) o_acc[n][j] = 0.f;
  float lsum[4] = {0.f, 0.f, 0.f, 0.f};

  const float scale = 0.10206207261596577f;  // 96^-0.5
  u16* pbh = pb[wv][0];
  u16* pbl = pb[wv][1];

  // stage records for kv-tile `it` into buffer nb (wave w does r = w*6..w*6+5)
  auto stage = [&](int nb, int it) {
    const long kbase = ((long)hl * 768 + (long)it * 12) * 512;  // (hl*128+it*2)*6
    const long vbase = ((long)hl * 768 + (long)it * 2) * 512;
#pragma unroll
    for (int j = 0; j < 6; ++j) {
      const int r = wv * 6 + j;
      const u16* src;
      if (r < 12) {
        const int tt = r / 6, rc = r % 6;  // rc = c*2+pl
        src = Kp + kbase + ((long)(tt * 6 + rc)) * 512 + lane * 8;
      } else {
        const int r2 = r - 12;  // n*2+pl
        src = Vp + vbase + ((long)((r2 >> 1) * 128 + (r2 & 1))) * 512 + lane * 8;
      }
      GLDS16(src, &kv[nb][r * 512]);
    }
  };

  stage(0, 0);
  __syncthreads();

  for (int it = 0; it < 64; ++it) {
    const int nb = it & 1;
    if (it < 63) stage(nb ^ 1, it + 1);
    const u16* L = kv[nb];

    f32x4 s0, s1;
#pragma unroll
    for (int j = 0; j < 4; ++j) { s0[j] = 0.f; s1[j] = 0.f; }
#pragma unroll
    for (int c = 0; c < 3; ++c) {
      const bf16x8 kh0 = ld16(L + (c * 2 + 0) * 512 + lane * 8);
      const bf16x8 kl0 = ld16(L + (c * 2 + 1) * 512 + lane * 8);
      const bf16x8 kh1 = ld16(L + (6 + c * 2 + 0) * 512 + lane * 8);
      const bf16x8 kl1 = ld16(L + (6 + c * 2 + 1) * 512 + lane * 8);
      s0 = MFMA(qh[c], kh0, s0);
      s1 = MFMA(qh[c], kh1, s1);
      s0 = MFMA(qh[c], kl0, s0);
      s1 = MFMA(qh[c], kl1, s1);
      s0 = MFMA(ql[c], kh0, s0);
      s1 = MFMA(ql[c], kh1, s1);
    }

    // max-free softmax: p = exp(s*scale - 12). C-layout: row lg*4+j,
    // col lr (s0) / lr+16 (s1). P stored transposed with unit-XOR swizzle:
    // stored_unit = unit ^ ((row&3)^(row>>2)).
#pragma unroll
    for (int j = 0; j < 4; ++j) {
      const float p0 = __expf(fmaf(s0[j], scale, -12.f));
      const float p1 = __expf(fmaf(s1[j], scale, -12.f));
      lsum[j] += p0 + p1;
      const int r = lg * 4 + j;
      const int key = j ^ lg;  // (r&3)^(r>>2)
      u16 h, l;
      split2(p0, h, l);
      const int a0 = r * 32 + ((((lr >> 3) ^ key) & 3) << 3) + (lr & 7);
      pbh[a0] = h;
      pbl[a0] = l;
      split2(p1, h, l);
      const int a1 = r * 32 + ((((2 + (lr >> 3)) ^ key) & 3) << 3) + (lr & 7);
      pbh[a1] = h;
      pbl[a1] = l;
    }
    // A-frag read: row lr, unit lg (swizzled)
    const int rkey = (lr & 3) ^ (lr >> 2);
    const int ra = lr * 32 + (((lg ^ rkey) & 3) << 3);
    const bf16x8 pah = ld16(&pbh[ra]);
    const bf16x8 pal = ld16(&pbl[ra]);

#pragma unroll
    for (int n = 0; n < 6; ++n) {
      const bf16x8 vh = ld16(L + (12 + n * 2 + 0) * 512 + lane * 8);
      const bf16x8 vl = ld16(L + (12 + n * 2 + 1) * 512 + lane * 8);
      o_acc[n] = MFMA(pah, vh, o_acc[n]);
      o_acc[n] = MFMA(pah, vl, o_acc[n]);
      o_acc[n] = MFMA(pal, vh, o_acc[n]);
    }
    __syncthreads();  // next buffer staged (vmcnt drain) + cur buffer free
  }

  // reduce l over the 16-lane (lr) group once
  float inv[4];
#pragma unroll
  for (int j = 0; j < 4; ++j) {
    float rs = lsum[j];
#pragma unroll
    for (int mk = 1; mk < 16; mk <<= 1) rs += __shfl_xor(rs, mk);
    inv[j] = 1.f / rs;
  }
#pragma unroll
  for (int n = 0; n < 6; ++n)
#pragma unroll
    for (int j = 0; j < 4; ++j) {
      const long row = (long)(b * 2048 + q0 + lg * 4 + j);
      const long col = (long)(hl & 31) * 96 + n * 16 + lr;
      u16 h, l;
      split2(o_acc[n][j] * inv[j], h, l);
      AOh[row * 3072 + col] = h;
      AOl[row * 3072 + col] = l;
    }
}

// ---------------------------------------------------------------- launch ---
extern "C" void kernel_launch(void* const* d_in, const int* in_sizes, int n_in,
                              void* d_out, int out_size, void* d_ws, size_t ws_size,
                              hipStream_t stream) {
  const float* x = (const float*)d_in[0];     // [4096][3072]
  const float* wqkv = (const float*)d_in[1];  // [9216][3072]
  const float* wo = (const float*)d_in[2];    // [3072][3072]
  const float* bo = (const float*)d_in[3];    // [3072]
  float* out = (float*)d_out;                 // [4096][3072]
  char* ws = (char*)d_ws;

  const size_t E_X = (size_t)4096 * 3072;
  const size_t E_WQ = (size_t)9216 * 3072;
  const size_t E_QKV = (size_t)4096 * 9216;

  // layout: [X planes | WQKV planes | QKV planes | Vpack]
  u16* XH = (u16*)ws;
  u16* XL = XH + E_X;
  char* W0 = ws + 4 * E_X;
  u16* WQH = (u16*)W0;
  u16* WQL = WQH + E_WQ;
  char* Q0 = W0 + 4 * E_WQ;
  u16* QKVH = (u16*)Q0;
  u16* QKVL = QKVH + E_QKV;
  char* V0 = Q0 + 4 * E_QKV;
  u16* VP = (u16*)V0;            // 48 MB pack (exact fit in 4*E_X region)
  u16* KP = (u16*)ws;            // reuses X region after GEMM1 (exact fit)
  // reuse of the dead WQKV region after GEMM1:
  u16* AOH = (u16*)W0;
  u16* AOL = AOH + E_X;
  u16* WOH = (u16*)(W0 + 4 * E_X);
  u16* WOL = WOH + (size_t)3072 * 3072;

  const size_t need = 4 * (E_X + E_WQ + E_QKV + E_X);
  if (ws_size < need) return;

  split_kernel<<<12288, 256, 0, stream>>>(x, XH, XL, (long)E_X);
  split_kernel<<<27648, 256, 0, stream>>>(wqkv, WQH, WQL, (long)E_WQ);
  gemm_nt_split<0><<<2304, 256, 0, stream>>>(XH, XL, WQH, WQL, 4096, 9216, 3072,
                                             QKVH, QKVL, nullptr, nullptr);
  pack_k<<<6144, 256, 0, stream>>>(QKVH, QKVL, KP);
  pack_v<<<4096, 256, 0, stream>>>(QKVH, QKVL, VP);
  split_kernel<<<9216, 256, 0, stream>>>(wo, WOH, WOL, (long)(3072 * 3072));
  attn_kernel<<<2048, 256, 0, stream>>>(QKVH, QKVL, KP, VP, AOH, AOL);
  gemm_nt_split<1><<<768, 256, 0, stream>>>(AOH, AOL, WOH, WOL, 4096, 3072, 3072,
                                            nullptr, nullptr, out, bo);
}